// Round 1
// baseline (657.020 us; speedup 1.0000x reference)
//
#include <hip/hip_runtime.h>
#include <hip/hip_bf16.h>

#define BB 32
#define LL 2048
#define DD 1024

typedef short short8 __attribute__((ext_vector_type(8)));
typedef float f32x4  __attribute__((ext_vector_type(4)));

__device__ __forceinline__ short f2bf(float f) {
    unsigned u = __float_as_uint(f);
    u += 0x7fffu + ((u >> 16) & 1u);      // round-to-nearest-even
    return (short)(u >> 16);
}

__device__ __forceinline__ float fast_tanh(float x) {
    float e = __expf(2.f * x);
    return 1.f - 2.f * __builtin_amdgcn_rcpf(e + 1.f);
}

// ---------- kernel 0: U_w fp32 -> bf16 (ws) ----------
__global__ void cvt_u_kernel(const float* __restrict__ U, short* __restrict__ Ubf) {
    int idx = (blockIdx.x * 256 + threadIdx.x) * 8;
    float4 a = *(const float4*)(U + idx);
    float4 c = *(const float4*)(U + idx + 4);
    short8 p;
    p[0] = f2bf(a.x); p[1] = f2bf(a.y); p[2] = f2bf(a.z); p[3] = f2bf(a.w);
    p[4] = f2bf(c.x); p[5] = f2bf(c.y); p[6] = f2bf(c.z); p[7] = f2bf(c.w);
    *(short8*)(Ubf + idx) = p;
}

// ---------- kernel 1: q'[b][d] = W_w[d,:]·h[b,:] + W_b[d] + U_b[d] ----------
__global__ void q_kernel(const float* __restrict__ dh, const float* __restrict__ Ww,
                         const float* __restrict__ Wb, const float* __restrict__ Ub,
                         float* __restrict__ qbuf) {
    int b  = blockIdx.x >> 4;
    int d0 = (blockIdx.x & 15) << 6;
    int t = threadIdx.x, w = t >> 6, lane = t & 63;
    __shared__ __align__(16) float hs[DD];
    *(float4*)&hs[t * 4] = *(const float4*)&dh[b * DD + t * 4];
    __syncthreads();
    float hr[16];
#pragma unroll
    for (int i = 0; i < 16; i++) hr[i] = hs[lane + 64 * i];
    for (int i = 0; i < 16; i++) {
        int d = d0 + w * 16 + i;
        const float* wr = Ww + (size_t)d * DD;
        float s = 0.f;
#pragma unroll
        for (int j = 0; j < 16; j++) s += wr[lane + 64 * j] * hr[j];
#pragma unroll
        for (int m = 1; m < 64; m <<= 1) s += __shfl_xor(s, m, 64);
        if (lane == 0) qbuf[b * DD + d] = s + Wb[d] + Ub[d];
    }
}

// ---------- kernel 2: fused scores GEMM ----------
// scores[b*L + l] += sum_d v[d] * tanh(q'[b][d] + sum_k U[d][k]*enc[b][l][k])
// Tile: 128 rows(M = b*l) x 128 cols(N = d), K-chunks of 32, 4 waves (2x2 of 64x64).
__global__ __launch_bounds__(256, 3) void gemm_scores_kernel(
    const float* __restrict__ enc, const short* __restrict__ Ubf,
    const float* __restrict__ qbuf, const float* __restrict__ vw,
    float* __restrict__ scores) {
    __shared__ __align__(16) short As[128 * 32];
    __shared__ __align__(16) short Bs[128 * 32];
    __shared__ float q_s[128], v_s[128], s_acc[128];

    const int t = threadIdx.x;
    const int lane = t & 63, w = t >> 6;
    const int l15 = lane & 15, quad = lane >> 4;
    const int wm = w >> 1, wn = w & 1;
    const int n0 = blockIdx.x << 7;
    const int m0 = blockIdx.y << 7;
    const int b  = m0 >> 11;                 // 128 | 2048 so one b per tile

    if (t < 128) {
        q_s[t] = qbuf[(b << 10) + n0 + t];
        v_s[t] = vw[n0 + t];
        s_acc[t] = 0.f;
    }

    f32x4 acc[4][4];
#pragma unroll
    for (int i = 0; i < 4; i++)
#pragma unroll
        for (int j = 0; j < 4; j++) acc[i][j] = (f32x4){0.f, 0.f, 0.f, 0.f};

    // A staging: 128 rows x 32 k fp32 -> bf16, 16 floats/thread
    const int arow = t >> 1, ahalf = t & 1;
    const float* aptr = enc + (((size_t)(m0 + arow)) << 10) + (ahalf << 4);
    short* adst = As + arow * 32 + ahalf * 16;
    // B staging: 128 rows x 32 k bf16, 16 bytes/thread x2
    const int brow = t >> 2, bks = (t & 3) * 8;
    const short* bptr1 = Ubf + ((size_t)(n0 + brow)) * 1024 + bks;
    const short* bptr2 = bptr1 + (size_t)64 * 1024;
    short* bdst1 = Bs + brow * 32 + bks;
    short* bdst2 = bdst1 + 64 * 32;

    for (int k0 = 0; k0 < 1024; k0 += 32) {
        __syncthreads();
        float4 f0 = *(const float4*)(aptr + k0);
        float4 f1 = *(const float4*)(aptr + k0 + 4);
        float4 f2 = *(const float4*)(aptr + k0 + 8);
        float4 f3 = *(const float4*)(aptr + k0 + 12);
        short8 p0, p1;
        p0[0] = f2bf(f0.x); p0[1] = f2bf(f0.y); p0[2] = f2bf(f0.z); p0[3] = f2bf(f0.w);
        p0[4] = f2bf(f1.x); p0[5] = f2bf(f1.y); p0[6] = f2bf(f1.z); p0[7] = f2bf(f1.w);
        p1[0] = f2bf(f2.x); p1[1] = f2bf(f2.y); p1[2] = f2bf(f2.z); p1[3] = f2bf(f2.w);
        p1[4] = f2bf(f3.x); p1[5] = f2bf(f3.y); p1[6] = f2bf(f3.z); p1[7] = f2bf(f3.w);
        *(short8*)adst = p0;
        *(short8*)(adst + 8) = p1;
        *(short8*)bdst1 = *(const short8*)(bptr1 + k0);
        *(short8*)bdst2 = *(const short8*)(bptr2 + k0);
        __syncthreads();

        short8 af[4], bfv[4];
#pragma unroll
        for (int mt = 0; mt < 4; mt++)
            af[mt] = *(const short8*)&As[(wm * 64 + mt * 16 + l15) * 32 + quad * 8];
#pragma unroll
        for (int nt = 0; nt < 4; nt++)
            bfv[nt] = *(const short8*)&Bs[(wn * 64 + nt * 16 + l15) * 32 + quad * 8];
#pragma unroll
        for (int mt = 0; mt < 4; mt++)
#pragma unroll
            for (int nt = 0; nt < 4; nt++)
                acc[mt][nt] = __builtin_amdgcn_mfma_f32_16x16x32_bf16(
                    af[mt], bfv[nt], acc[mt][nt], 0, 0, 0);
    }

    // epilogue: tanh + v-dot, reduce over cols
    float qn[4], vn[4];
#pragma unroll
    for (int nt = 0; nt < 4; nt++) {
        qn[nt] = q_s[wn * 64 + nt * 16 + l15];
        vn[nt] = v_s[wn * 64 + nt * 16 + l15];
    }
#pragma unroll
    for (int mt = 0; mt < 4; mt++) {
#pragma unroll
        for (int r = 0; r < 4; r++) {
            float sum = 0.f;
#pragma unroll
            for (int nt = 0; nt < 4; nt++) {
                float x = acc[mt][nt][r] + qn[nt];
                sum += vn[nt] * fast_tanh(x);
            }
            sum += __shfl_xor(sum, 1, 64);
            sum += __shfl_xor(sum, 2, 64);
            sum += __shfl_xor(sum, 4, 64);
            sum += __shfl_xor(sum, 8, 64);
            if (l15 == 0)
                atomicAdd(&s_acc[wm * 64 + mt * 16 + quad * 4 + r], sum);
        }
    }
    __syncthreads();
    if (t < 128) atomicAdd(&scores[m0 + t], s_acc[t]);
}

// ---------- kernel 3: softmax over L per b -> attn output ----------
__global__ void softmax_kernel(const float* __restrict__ scores, float* __restrict__ attn) {
    int b = blockIdx.x, t = threadIdx.x;
    int w = t >> 6, lane = t & 63;
    __shared__ float rm[4], rs[4];
    float v[8];
#pragma unroll
    for (int i = 0; i < 8; i++) v[i] = scores[(b << 11) + t + (i << 8)];
    float m = v[0];
#pragma unroll
    for (int i = 1; i < 8; i++) m = fmaxf(m, v[i]);
#pragma unroll
    for (int s = 1; s < 64; s <<= 1) m = fmaxf(m, __shfl_xor(m, s, 64));
    if (lane == 0) rm[w] = m;
    __syncthreads();
    m = fmaxf(fmaxf(rm[0], rm[1]), fmaxf(rm[2], rm[3]));
    float s = 0.f;
#pragma unroll
    for (int i = 0; i < 8; i++) { v[i] = __expf(v[i] - m); s += v[i]; }
#pragma unroll
    for (int k = 1; k < 64; k <<= 1) s += __shfl_xor(s, k, 64);
    if (lane == 0) rs[w] = s;
    __syncthreads();
    s = rs[0] + rs[1] + rs[2] + rs[3];
    float inv = 1.f / s;
#pragma unroll
    for (int i = 0; i < 8; i++) attn[(b << 11) + t + (i << 8)] = v[i] * inv;
}

// ---------- kernel 4: context[b][d] = sum_l attn[b][l]*enc[b][l][d] ----------
__global__ void context_kernel(const float* __restrict__ enc, const float* __restrict__ attn,
                               float* __restrict__ ctx) {
    int dchunk = blockIdx.x, lsp = blockIdx.y, b = blockIdx.z;
    int t = threadIdx.x;
    int d4 = (t & 31) << 2;   // 0..124
    int dl = t >> 5;          // 0..7
    int lbase = lsp << 9;     // 512 l per block
    __shared__ __align__(16) float at_s[512];
    at_s[t] = attn[(b << 11) + lbase + t];
    at_s[t + 256] = attn[(b << 11) + lbase + t + 256];
    __syncthreads();
    int d0 = dchunk << 7;
    float ax = 0.f, ay = 0.f, az = 0.f, aw = 0.f;
    const float* base = enc + (((size_t)(b << 11) + lbase) << 10) + d0 + d4;
#pragma unroll 4
    for (int i = 0; i < 64; i++) {
        int l = (i << 3) + dl;
        float wgt = at_s[l];
        float4 e = *(const float4*)(base + ((size_t)l << 10));
        ax += wgt * e.x; ay += wgt * e.y; az += wgt * e.z; aw += wgt * e.w;
    }
    float* o = ctx + (b << 10) + d0 + d4;
    atomicAdd(o + 0, ax);
    atomicAdd(o + 1, ay);
    atomicAdd(o + 2, az);
    atomicAdd(o + 3, aw);
}

extern "C" void kernel_launch(void* const* d_in, const int* in_sizes, int n_in,
                              void* d_out, int out_size, void* d_ws, size_t ws_size,
                              hipStream_t stream) {
    const float* dh  = (const float*)d_in[0];  // [32,1,1024]
    const float* enc = (const float*)d_in[1];  // [32,2048,1024]
    const float* Ww  = (const float*)d_in[2];  // [1024,1024]
    const float* Wb  = (const float*)d_in[3];  // [1024]
    const float* Uw  = (const float*)d_in[4];  // [1024,1024]
    const float* Ub  = (const float*)d_in[5];  // [1024]
    const float* vw  = (const float*)d_in[6];  // [1,1024]
    // d_in[7] = v_b: dropped (softmax shift-invariance; affects neither output)

    float* out  = (float*)d_out;               // [0,32768) context, [32768,98304) attn
    char*  ws   = (char*)d_ws;
    short* Ubf    = (short*)ws;                          // 2 MB
    float* qbuf   = (float*)(ws + (1 << 21));            // 128 KB
    float* scores = (float*)(ws + (1 << 21) + (1 << 17)); // 256 KB

    hipMemsetAsync(scores, 0, (size_t)BB * LL * sizeof(float), stream);
    hipMemsetAsync(out, 0, (size_t)BB * DD * sizeof(float), stream);

    cvt_u_kernel<<<512, 256, 0, stream>>>(Uw, Ubf);
    q_kernel<<<512, 256, 0, stream>>>(dh, Ww, Wb, Ub, qbuf);
    gemm_scores_kernel<<<dim3(8, 512), 256, 0, stream>>>(enc, Ubf, qbuf, vw, scores);
    softmax_kernel<<<BB, 256, 0, stream>>>(scores, out + BB * DD);
    context_kernel<<<dim3(8, 4, BB), 256, 0, stream>>>(enc, out + BB * DD, out);
}

// Round 2
// 637.685 us; speedup vs baseline: 1.0303x; 1.0303x over previous
//
#include <hip/hip_runtime.h>
#include <hip/hip_bf16.h>
#include <stdint.h>

#define BB 32
#define LL 2048
#define DD 1024

typedef short short8 __attribute__((ext_vector_type(8)));
typedef float f32x4  __attribute__((ext_vector_type(4)));

__device__ __forceinline__ short f2bf(float f) {
    unsigned u = __float_as_uint(f);
    u += 0x7fffu + ((u >> 16) & 1u);      // round-to-nearest-even
    return (short)(u >> 16);
}

__device__ __forceinline__ float fast_tanh(float x) {
    float e = __expf(2.f * x);
    return 1.f - 2.f * __builtin_amdgcn_rcpf(e + 1.f);
}

// async global->LDS, 16B per lane; LDS dst = wave-uniform base + lane*16
__device__ __forceinline__ void async_cp16(const void* g, void* l) {
    __builtin_amdgcn_global_load_lds(
        (__attribute__((address_space(1))) void*)g,
        (__attribute__((address_space(3))) void*)l, 16, 0, 0);
}

// ---------- generic fp32 -> bf16 (8 elems/thread) ----------
__global__ void cvt_bf16_kernel(const float* __restrict__ src, short* __restrict__ dst) {
    int idx = (blockIdx.x * 256 + threadIdx.x) * 8;
    float4 a = *(const float4*)(src + idx);
    float4 c = *(const float4*)(src + idx + 4);
    short8 p;
    p[0] = f2bf(a.x); p[1] = f2bf(a.y); p[2] = f2bf(a.z); p[3] = f2bf(a.w);
    p[4] = f2bf(c.x); p[5] = f2bf(c.y); p[6] = f2bf(c.z); p[7] = f2bf(c.w);
    *(short8*)(dst + idx) = p;
}

// ---------- q'[b][d] = W_w[d,:]·h[b,:] + W_b[d] + U_b[d] ----------
__global__ void q_kernel(const float* __restrict__ dh, const float* __restrict__ Ww,
                         const float* __restrict__ Wb, const float* __restrict__ Ub,
                         float* __restrict__ qbuf) {
    int b  = blockIdx.x >> 4;
    int d0 = (blockIdx.x & 15) << 6;
    int t = threadIdx.x, w = t >> 6, lane = t & 63;
    __shared__ __align__(16) float hs[DD];
    *(float4*)&hs[t * 4] = *(const float4*)&dh[b * DD + t * 4];
    __syncthreads();
    float hr[16];
#pragma unroll
    for (int i = 0; i < 16; i++) hr[i] = hs[lane + 64 * i];
    for (int i = 0; i < 16; i++) {
        int d = d0 + w * 16 + i;
        const float* wr = Ww + (size_t)d * DD;
        float s = 0.f;
#pragma unroll
        for (int j = 0; j < 16; j++) s += wr[lane + 64 * j] * hr[j];
#pragma unroll
        for (int m = 1; m < 64; m <<= 1) s += __shfl_xor(s, m, 64);
        if (lane == 0) qbuf[b * DD + d] = s + Wb[d] + Ub[d];
    }
}

// ---------- Path A: bf16-enc GEMM with async LDS staging ----------
// spart[nblk][b*L + l] = sum_{d in nblk} v[d] * tanh(q'[b][d] + U[d,:]·enc[b][l,:])
__global__ __launch_bounds__(256, 3) void gemm_scores_bf(
    const short* __restrict__ encbf, const short* __restrict__ Ubf,
    const float* __restrict__ qbuf, const float* __restrict__ vw,
    float* __restrict__ spart) {
    __shared__ __align__(16) short As[128 * 32];
    __shared__ __align__(16) short Bs[128 * 32];
    __shared__ float q_s[128], v_s[128], s_acc[2][128];

    const int t = threadIdx.x;
    const int lane = t & 63, w = t >> 6;
    const int l15 = lane & 15, quad = lane >> 4;
    const int wm = w >> 1, wn = w & 1;
    const int n0 = blockIdx.x << 7;
    const int m0 = blockIdx.y << 7;
    const int b  = m0 >> 11;

    if (t < 128) {
        q_s[t] = qbuf[(b << 10) + n0 + t];
        v_s[t] = vw[n0 + t];
    }

    f32x4 acc[4][4];
#pragma unroll
    for (int i = 0; i < 4; i++)
#pragma unroll
        for (int j = 0; j < 4; j++) acc[i][j] = (f32x4){0.f, 0.f, 0.f, 0.f};

    // staging: wave w covers 32 rows (2 issues of 16 rows); lane -> (row=lane/4, 16B seg=lane%4)
    const int srow = lane >> 2, sseg = (lane & 3) << 3;
    const short* gA0 = encbf + (((size_t)(m0 + w * 32 + srow)) << 10) + sseg;
    const short* gB0 = Ubf   + (((size_t)(n0 + w * 32 + srow)) << 10) + sseg;
    short* lA0 = As + w * 32 * 32;
    short* lB0 = Bs + w * 32 * 32;

    for (int k0 = 0; k0 < 1024; k0 += 32) {
        __syncthreads();
        async_cp16(gA0 + k0, lA0);
        async_cp16(gA0 + k0 + (16 << 10), lA0 + 16 * 32);
        async_cp16(gB0 + k0, lB0);
        async_cp16(gB0 + k0 + (16 << 10), lB0 + 16 * 32);
        __syncthreads();

        short8 af[4], bfv[4];
#pragma unroll
        for (int mt = 0; mt < 4; mt++)
            af[mt] = *(const short8*)&As[(wm * 64 + mt * 16 + l15) * 32 + quad * 8];
#pragma unroll
        for (int nt = 0; nt < 4; nt++)
            bfv[nt] = *(const short8*)&Bs[(wn * 64 + nt * 16 + l15) * 32 + quad * 8];
#pragma unroll
        for (int mt = 0; mt < 4; mt++)
#pragma unroll
            for (int nt = 0; nt < 4; nt++)
                acc[mt][nt] = __builtin_amdgcn_mfma_f32_16x16x32_bf16(
                    af[mt], bfv[nt], acc[mt][nt], 0, 0, 0);
    }

    float qn[4], vn[4];
#pragma unroll
    for (int nt = 0; nt < 4; nt++) {
        qn[nt] = q_s[wn * 64 + nt * 16 + l15];
        vn[nt] = v_s[wn * 64 + nt * 16 + l15];
    }
#pragma unroll
    for (int mt = 0; mt < 4; mt++) {
#pragma unroll
        for (int r = 0; r < 4; r++) {
            float sum = 0.f;
#pragma unroll
            for (int nt = 0; nt < 4; nt++)
                sum += vn[nt] * fast_tanh(acc[mt][nt][r] + qn[nt]);
            sum += __shfl_xor(sum, 1, 64);
            sum += __shfl_xor(sum, 2, 64);
            sum += __shfl_xor(sum, 4, 64);
            sum += __shfl_xor(sum, 8, 64);
            if (l15 == 0)
                s_acc[wn][wm * 64 + mt * 16 + quad * 4 + r] = sum;
        }
    }
    __syncthreads();
    if (t < 128)
        spart[((size_t)blockIdx.x << 16) + m0 + t] = s_acc[0][t] + s_acc[1][t];
}

// ---------- Path B fallback: round-1 fp32-enc GEMM (atomics into scores) ----------
__global__ __launch_bounds__(256, 3) void gemm_scores_f32(
    const float* __restrict__ enc, const short* __restrict__ Ubf,
    const float* __restrict__ qbuf, const float* __restrict__ vw,
    float* __restrict__ scores) {
    __shared__ __align__(16) short As[128 * 32];
    __shared__ __align__(16) short Bs[128 * 32];
    __shared__ float q_s[128], v_s[128], s_acc[128];

    const int t = threadIdx.x;
    const int lane = t & 63, w = t >> 6;
    const int l15 = lane & 15, quad = lane >> 4;
    const int wm = w >> 1, wn = w & 1;
    const int n0 = blockIdx.x << 7;
    const int m0 = blockIdx.y << 7;
    const int b  = m0 >> 11;

    if (t < 128) {
        q_s[t] = qbuf[(b << 10) + n0 + t];
        v_s[t] = vw[n0 + t];
        s_acc[t] = 0.f;
    }

    f32x4 acc[4][4];
#pragma unroll
    for (int i = 0; i < 4; i++)
#pragma unroll
        for (int j = 0; j < 4; j++) acc[i][j] = (f32x4){0.f, 0.f, 0.f, 0.f};

    const int arow = t >> 1, ahalf = t & 1;
    const float* aptr = enc + (((size_t)(m0 + arow)) << 10) + (ahalf << 4);
    short* adst = As + arow * 32 + ahalf * 16;
    const int brow = t >> 2, bks = (t & 3) * 8;
    const short* bptr1 = Ubf + ((size_t)(n0 + brow)) * 1024 + bks;
    const short* bptr2 = bptr1 + (size_t)64 * 1024;
    short* bdst1 = Bs + brow * 32 + bks;
    short* bdst2 = bdst1 + 64 * 32;

    for (int k0 = 0; k0 < 1024; k0 += 32) {
        __syncthreads();
        float4 f0 = *(const float4*)(aptr + k0);
        float4 f1 = *(const float4*)(aptr + k0 + 4);
        float4 f2 = *(const float4*)(aptr + k0 + 8);
        float4 f3 = *(const float4*)(aptr + k0 + 12);
        short8 p0, p1;
        p0[0] = f2bf(f0.x); p0[1] = f2bf(f0.y); p0[2] = f2bf(f0.z); p0[3] = f2bf(f0.w);
        p0[4] = f2bf(f1.x); p0[5] = f2bf(f1.y); p0[6] = f2bf(f1.z); p0[7] = f2bf(f1.w);
        p1[0] = f2bf(f2.x); p1[1] = f2bf(f2.y); p1[2] = f2bf(f2.z); p1[3] = f2bf(f2.w);
        p1[4] = f2bf(f3.x); p1[5] = f2bf(f3.y); p1[6] = f2bf(f3.z); p1[7] = f2bf(f3.w);
        *(short8*)adst = p0;
        *(short8*)(adst + 8) = p1;
        *(short8*)bdst1 = *(const short8*)(bptr1 + k0);
        *(short8*)bdst2 = *(const short8*)(bptr2 + k0);
        __syncthreads();

        short8 af[4], bfv[4];
#pragma unroll
        for (int mt = 0; mt < 4; mt++)
            af[mt] = *(const short8*)&As[(wm * 64 + mt * 16 + l15) * 32 + quad * 8];
#pragma unroll
        for (int nt = 0; nt < 4; nt++)
            bfv[nt] = *(const short8*)&Bs[(wn * 64 + nt * 16 + l15) * 32 + quad * 8];
#pragma unroll
        for (int mt = 0; mt < 4; mt++)
#pragma unroll
            for (int nt = 0; nt < 4; nt++)
                acc[mt][nt] = __builtin_amdgcn_mfma_f32_16x16x32_bf16(
                    af[mt], bfv[nt], acc[mt][nt], 0, 0, 0);
    }

    float qn[4], vn[4];
#pragma unroll
    for (int nt = 0; nt < 4; nt++) {
        qn[nt] = q_s[wn * 64 + nt * 16 + l15];
        vn[nt] = v_s[wn * 64 + nt * 16 + l15];
    }
#pragma unroll
    for (int mt = 0; mt < 4; mt++) {
#pragma unroll
        for (int r = 0; r < 4; r++) {
            float sum = 0.f;
#pragma unroll
            for (int nt = 0; nt < 4; nt++)
                sum += vn[nt] * fast_tanh(acc[mt][nt][r] + qn[nt]);
            sum += __shfl_xor(sum, 1, 64);
            sum += __shfl_xor(sum, 2, 64);
            sum += __shfl_xor(sum, 4, 64);
            sum += __shfl_xor(sum, 8, 64);
            if (l15 == 0)
                atomicAdd(&s_acc[wm * 64 + mt * 16 + quad * 4 + r], sum);
        }
    }
    __syncthreads();
    if (t < 128) atomicAdd(&scores[m0 + t], s_acc[t]);
}

// ---------- softmax over L per b (sums npart partial score slabs) ----------
__global__ void softmax_kernel(const float* __restrict__ sp, int npart,
                               float* __restrict__ attn) {
    int b = blockIdx.x, t = threadIdx.x;
    int w = t >> 6, lane = t & 63;
    __shared__ float rm[4], rs[4];
    float v[8];
#pragma unroll
    for (int i = 0; i < 8; i++) {
        float s = 0.f;
        for (int p = 0; p < npart; p++) s += sp[p * 65536 + (b << 11) + t + (i << 8)];
        v[i] = s;
    }
    float m = v[0];
#pragma unroll
    for (int i = 1; i < 8; i++) m = fmaxf(m, v[i]);
#pragma unroll
    for (int s = 1; s < 64; s <<= 1) m = fmaxf(m, __shfl_xor(m, s, 64));
    if (lane == 0) rm[w] = m;
    __syncthreads();
    m = fmaxf(fmaxf(rm[0], rm[1]), fmaxf(rm[2], rm[3]));
    float s = 0.f;
#pragma unroll
    for (int i = 0; i < 8; i++) { v[i] = __expf(v[i] - m); s += v[i]; }
#pragma unroll
    for (int k = 1; k < 64; k <<= 1) s += __shfl_xor(s, k, 64);
    if (lane == 0) rs[w] = s;
    __syncthreads();
    s = rs[0] + rs[1] + rs[2] + rs[3];
    float inv = 1.f / s;
#pragma unroll
    for (int i = 0; i < 8; i++) attn[(b << 11) + t + (i << 8)] = v[i] * inv;
}

// ---------- context[b][d] = sum_l attn[b][l]*enc[b][l][d], atomic-free ----------
__global__ void context_kernel(const float* __restrict__ enc, const float* __restrict__ attn,
                               float* __restrict__ ctx) {
    int dchunk = blockIdx.x, b = blockIdx.y;
    int t = threadIdx.x;                       // 0..511
    __shared__ __align__(16) float at_s[2048];
    __shared__ float red[16][128];
    *(float4*)&at_s[t * 4] = *(const float4*)&attn[(b << 11) + t * 4];
    __syncthreads();
    int d4 = (t & 31) << 2;                    // 0..124
    int dl = t >> 5;                           // 0..15
    int d0 = dchunk << 7;
    const float* base = enc + ((size_t)b << 21) + d0 + d4;
    float ax = 0.f, ay = 0.f, az = 0.f, aw = 0.f;
#pragma unroll 4
    for (int i = 0; i < 128; i++) {
        int l = (i << 4) + dl;
        float wg = at_s[l];
        float4 e = *(const float4*)(base + ((size_t)l << 10));
        ax += wg * e.x; ay += wg * e.y; az += wg * e.z; aw += wg * e.w;
    }
    red[dl][d4 + 0] = ax;
    red[dl][d4 + 1] = ay;
    red[dl][d4 + 2] = az;
    red[dl][d4 + 3] = aw;
    __syncthreads();
    if (t < 128) {
        float s = 0.f;
#pragma unroll
        for (int j = 0; j < 16; j++) s += red[j][t];
        ctx[(b << 10) + d0 + t] = s;
    }
}

extern "C" void kernel_launch(void* const* d_in, const int* in_sizes, int n_in,
                              void* d_out, int out_size, void* d_ws, size_t ws_size,
                              hipStream_t stream) {
    const float* dh  = (const float*)d_in[0];  // [32,1,1024]
    const float* enc = (const float*)d_in[1];  // [32,2048,1024]
    const float* Ww  = (const float*)d_in[2];  // [1024,1024]
    const float* Wb  = (const float*)d_in[3];  // [1024]
    const float* Uw  = (const float*)d_in[4];  // [1024,1024]
    const float* Ub  = (const float*)d_in[5];  // [1024]
    const float* vw  = (const float*)d_in[6];  // [1,1024]
    // d_in[7] = v_b: dropped (softmax shift-invariance; affects neither output)

    float* out  = (float*)d_out;               // [0,32768) context, [32768,98304) attn
    float* attn = out + BB * DD;
    char*  ws   = (char*)d_ws;
    short* Ubf   = (short*)ws;                           // 2 MB
    float* qbuf  = (float*)(ws + (2 << 20));             // 128 KB
    float* sbuf  = (float*)(ws + (2 << 20) + (1 << 17)); // 2 MB (A: 8 slabs) / 256 KB (B)
    short* encbf = (short*)(ws + (8 << 20));             // 134.2 MB (Path A only)

    bool bigws = ws_size >= ((size_t)143 << 20);

    cvt_bf16_kernel<<<512, 256, 0, stream>>>(Uw, Ubf);
    q_kernel<<<512, 256, 0, stream>>>(dh, Ww, Wb, Ub, qbuf);

    if (bigws) {
        cvt_bf16_kernel<<<32768, 256, 0, stream>>>(enc, encbf);
        gemm_scores_bf<<<dim3(8, 512), 256, 0, stream>>>(encbf, Ubf, qbuf, vw, sbuf);
        softmax_kernel<<<BB, 256, 0, stream>>>(sbuf, 8, attn);
    } else {
        hipMemsetAsync(sbuf, 0, (size_t)BB * LL * sizeof(float), stream);
        gemm_scores_f32<<<dim3(8, 512), 256, 0, stream>>>(enc, Ubf, qbuf, vw, sbuf);
        softmax_kernel<<<BB, 256, 0, stream>>>(sbuf, 1, attn);
    }
    context_kernel<<<dim3(8, BB), 512, 0, stream>>>(enc, attn, out);
}

// Round 3
// 592.856 us; speedup vs baseline: 1.1082x; 1.0756x over previous
//
#include <hip/hip_runtime.h>
#include <hip/hip_bf16.h>
#include <stdint.h>

#define BB 32
#define LL 2048
#define DD 1024

typedef short short8  __attribute__((ext_vector_type(8)));
typedef float f32x4   __attribute__((ext_vector_type(4)));

__device__ __forceinline__ short f2bf(float f) {
    unsigned u = __float_as_uint(f);
    u += 0x7fffu + ((u >> 16) & 1u);      // round-to-nearest-even
    return (short)(u >> 16);
}

__device__ __forceinline__ float bf2f(unsigned short s) {
    return __uint_as_float(((unsigned)s) << 16);
}

__device__ __forceinline__ float fast_tanh(float x) {
    float e = __expf(2.f * x);
    return 1.f - 2.f * __builtin_amdgcn_rcpf(e + 1.f);
}

__device__ __forceinline__ void async_cp16(const void* g, void* l) {
    __builtin_amdgcn_global_load_lds(
        (__attribute__((address_space(1))) void*)g,
        (__attribute__((address_space(3))) void*)l, 16, 0, 0);
}

// ---------- generic fp32 -> bf16 (8 elems/thread) ----------
__global__ void cvt_bf16_kernel(const float* __restrict__ src, short* __restrict__ dst) {
    int idx = (blockIdx.x * 256 + threadIdx.x) * 8;
    float4 a = *(const float4*)(src + idx);
    float4 c = *(const float4*)(src + idx + 4);
    short8 p;
    p[0] = f2bf(a.x); p[1] = f2bf(a.y); p[2] = f2bf(a.z); p[3] = f2bf(a.w);
    p[4] = f2bf(c.x); p[5] = f2bf(c.y); p[6] = f2bf(c.z); p[7] = f2bf(c.w);
    *(short8*)(dst + idx) = p;
}

// ---------- q'[b][d] = W_w[d,:]·h[b,:] + W_b[d] + U_b[d] ----------
__global__ void q_kernel(const float* __restrict__ dh, const float* __restrict__ Ww,
                         const float* __restrict__ Wb, const float* __restrict__ Ub,
                         float* __restrict__ qbuf) {
    int b  = blockIdx.x >> 4;
    int d0 = (blockIdx.x & 15) << 6;
    int t = threadIdx.x, w = t >> 6, lane = t & 63;
    __shared__ __align__(16) float hs[DD];
    *(float4*)&hs[t * 4] = *(const float4*)&dh[b * DD + t * 4];
    __syncthreads();
    float hr[16];
#pragma unroll
    for (int i = 0; i < 16; i++) hr[i] = hs[lane + 64 * i];
    for (int i = 0; i < 16; i++) {
        int d = d0 + w * 16 + i;
        const float* wr = Ww + (size_t)d * DD;
        float s = 0.f;
#pragma unroll
        for (int j = 0; j < 16; j++) s += wr[lane + 64 * j] * hr[j];
#pragma unroll
        for (int m = 1; m < 64; m <<= 1) s += __shfl_xor(s, m, 64);
        if (lane == 0) qbuf[b * DD + d] = s + Wb[d] + Ub[d];
    }
}

// ---------- Path A: bf16-enc GEMM, XCD-swizzled for A-stripe L2 reuse ----------
__global__ __launch_bounds__(256, 3) void gemm_scores_bf(
    const short* __restrict__ encbf, const short* __restrict__ Ubf,
    const float* __restrict__ qbuf, const float* __restrict__ vw,
    float* __restrict__ spart) {
    __shared__ __align__(16) short As[128 * 32];
    __shared__ __align__(16) short Bs[128 * 32];
    __shared__ float q_s[128], v_s[128], s_acc[2][128];

    const int t = threadIdx.x;
    const int lane = t & 63, w = t >> 6;
    const int l15 = lane & 15, quad = lane >> 4;
    const int wm = w >> 1, wn = w & 1;

    // XCD swizzle: blocks dispatch round-robin to 8 XCDs by linear id.
    // Keep the 8 n-blocks of one m-stripe on ONE XCD (consecutive slots there)
    // so the 256 KB A-stripe is fetched into a single L2.
    const int lin  = blockIdx.x + (blockIdx.y << 3);   // 0..4095
    const int xcd  = lin & 7;
    const int slot = lin >> 3;                          // 0..511
    const int nblk = slot & 7;
    const int mstripe = (xcd << 6) + (slot >> 3);       // 0..511
    const int n0 = nblk << 7;
    const int m0 = mstripe << 7;
    const int b  = m0 >> 11;

    if (t < 128) {
        q_s[t] = qbuf[(b << 10) + n0 + t];
        v_s[t] = vw[n0 + t];
    }

    f32x4 acc[4][4];
#pragma unroll
    for (int i = 0; i < 4; i++)
#pragma unroll
        for (int j = 0; j < 4; j++) acc[i][j] = (f32x4){0.f, 0.f, 0.f, 0.f};

    const int srow = lane >> 2, sseg = (lane & 3) << 3;
    const short* gA0 = encbf + (((size_t)(m0 + w * 32 + srow)) << 10) + sseg;
    const short* gB0 = Ubf   + (((size_t)(n0 + w * 32 + srow)) << 10) + sseg;
    short* lA0 = As + w * 32 * 32;
    short* lB0 = Bs + w * 32 * 32;

    for (int k0 = 0; k0 < 1024; k0 += 32) {
        __syncthreads();
        async_cp16(gA0 + k0, lA0);
        async_cp16(gA0 + k0 + (16 << 10), lA0 + 16 * 32);
        async_cp16(gB0 + k0, lB0);
        async_cp16(gB0 + k0 + (16 << 10), lB0 + 16 * 32);
        __syncthreads();

        short8 af[4], bfv[4];
#pragma unroll
        for (int mt = 0; mt < 4; mt++)
            af[mt] = *(const short8*)&As[(wm * 64 + mt * 16 + l15) * 32 + quad * 8];
#pragma unroll
        for (int nt = 0; nt < 4; nt++)
            bfv[nt] = *(const short8*)&Bs[(wn * 64 + nt * 16 + l15) * 32 + quad * 8];
#pragma unroll
        for (int mt = 0; mt < 4; mt++)
#pragma unroll
            for (int nt = 0; nt < 4; nt++)
                acc[mt][nt] = __builtin_amdgcn_mfma_f32_16x16x32_bf16(
                    af[mt], bfv[nt], acc[mt][nt], 0, 0, 0);
    }

    float qn[4], vn[4];
#pragma unroll
    for (int nt = 0; nt < 4; nt++) {
        qn[nt] = q_s[wn * 64 + nt * 16 + l15];
        vn[nt] = v_s[wn * 64 + nt * 16 + l15];
    }
#pragma unroll
    for (int mt = 0; mt < 4; mt++) {
#pragma unroll
        for (int r = 0; r < 4; r++) {
            float sum = 0.f;
#pragma unroll
            for (int nt = 0; nt < 4; nt++)
                sum += vn[nt] * fast_tanh(acc[mt][nt][r] + qn[nt]);
            sum += __shfl_xor(sum, 1, 64);
            sum += __shfl_xor(sum, 2, 64);
            sum += __shfl_xor(sum, 4, 64);
            sum += __shfl_xor(sum, 8, 64);
            if (l15 == 0)
                s_acc[wn][wm * 64 + mt * 16 + quad * 4 + r] = sum;
        }
    }
    __syncthreads();
    if (t < 128)
        spart[((size_t)nblk << 16) + m0 + t] = s_acc[0][t] + s_acc[1][t];
}

// ---------- Path A: fused softmax + context (reads bf16 enc, L3-resident) ----------
// grid (8 dchunks, 32 b), 512 threads. Each block recomputes b's softmax (cheap),
// dchunk 0 writes attn; all blocks do the attn-weighted sum over their 128 d cols.
__global__ void ctx_softmax_bf(const float* __restrict__ sp, const short* __restrict__ encbf,
                               float* __restrict__ attn, float* __restrict__ ctx) {
    const int dchunk = blockIdx.x, b = blockIdx.y;
    const int t = threadIdx.x;                 // 0..511
    const int w = t >> 6, lane = t & 63;
    __shared__ float at_s[2048];
    __shared__ float red[16][128];
    __shared__ float rr[8];

    // scores for this b: sum of the 8 n-partials
    float v[4];
#pragma unroll
    for (int i = 0; i < 4; i++) {
        int l = t + (i << 9);
        float s = 0.f;
#pragma unroll
        for (int p = 0; p < 8; p++) s += sp[(p << 16) + (b << 11) + l];
        v[i] = s;
    }
    float m = fmaxf(fmaxf(v[0], v[1]), fmaxf(v[2], v[3]));
#pragma unroll
    for (int s = 1; s < 64; s <<= 1) m = fmaxf(m, __shfl_xor(m, s, 64));
    if (lane == 0) rr[w] = m;
    __syncthreads();
    m = rr[0];
#pragma unroll
    for (int i = 1; i < 8; i++) m = fmaxf(m, rr[i]);
    float s = 0.f;
#pragma unroll
    for (int i = 0; i < 4; i++) { v[i] = __expf(v[i] - m); s += v[i]; }
#pragma unroll
    for (int k = 1; k < 64; k <<= 1) s += __shfl_xor(s, k, 64);
    __syncthreads();
    if (lane == 0) rr[w] = s;
#pragma unroll
    for (int i = 0; i < 4; i++) at_s[t + (i << 9)] = v[i];
    __syncthreads();
    s = 0.f;
#pragma unroll
    for (int i = 0; i < 8; i++) s += rr[i];
    float inv = 1.f / s;

    if (dchunk == 0) {
#pragma unroll
        for (int i = 0; i < 4; i++) attn[(b << 11) + t + (i << 9)] = v[i] * inv;
    }

    // weighted sum: cols d0+d4..d0+d4+3, rows l = i*16 + dl
    const int d4 = (t & 31) << 2;
    const int dl = t >> 5;                     // 0..15
    const int d0 = dchunk << 7;
    const short* base = encbf + ((size_t)b << 21) + d0 + d4;
    float ax = 0.f, ay = 0.f, az = 0.f, aw = 0.f;
#pragma unroll 4
    for (int i = 0; i < 128; i++) {
        int l = (i << 4) + dl;
        float wg = at_s[l];
        ushort4 e = *(const ushort4*)(base + ((size_t)l << 10));
        ax += wg * bf2f(e.x); ay += wg * bf2f(e.y);
        az += wg * bf2f(e.z); aw += wg * bf2f(e.w);
    }
    red[dl][d4 + 0] = ax;
    red[dl][d4 + 1] = ay;
    red[dl][d4 + 2] = az;
    red[dl][d4 + 3] = aw;
    __syncthreads();
    if (t < 128) {
        float acc = 0.f;
#pragma unroll
        for (int j = 0; j < 16; j++) acc += red[j][t];
        ctx[(b << 10) + d0 + t] = acc * inv;
    }
}

// ---------- Path B fallback (small ws): fp32-enc GEMM + separate softmax/context ----------
__global__ __launch_bounds__(256, 3) void gemm_scores_f32(
    const float* __restrict__ enc, const short* __restrict__ Ubf,
    const float* __restrict__ qbuf, const float* __restrict__ vw,
    float* __restrict__ scores) {
    __shared__ __align__(16) short As[128 * 32];
    __shared__ __align__(16) short Bs[128 * 32];
    __shared__ float q_s[128], v_s[128], s_acc[128];

    const int t = threadIdx.x;
    const int lane = t & 63, w = t >> 6;
    const int l15 = lane & 15, quad = lane >> 4;
    const int wm = w >> 1, wn = w & 1;
    const int n0 = blockIdx.x << 7;
    const int m0 = blockIdx.y << 7;
    const int b  = m0 >> 11;

    if (t < 128) {
        q_s[t] = qbuf[(b << 10) + n0 + t];
        v_s[t] = vw[n0 + t];
        s_acc[t] = 0.f;
    }

    f32x4 acc[4][4];
#pragma unroll
    for (int i = 0; i < 4; i++)
#pragma unroll
        for (int j = 0; j < 4; j++) acc[i][j] = (f32x4){0.f, 0.f, 0.f, 0.f};

    const int arow = t >> 1, ahalf = t & 1;
    const float* aptr = enc + (((size_t)(m0 + arow)) << 10) + (ahalf << 4);
    short* adst = As + arow * 32 + ahalf * 16;
    const int brow = t >> 2, bks = (t & 3) * 8;
    const short* bptr1 = Ubf + ((size_t)(n0 + brow)) * 1024 + bks;
    const short* bptr2 = bptr1 + (size_t)64 * 1024;
    short* bdst1 = Bs + brow * 32 + bks;
    short* bdst2 = bdst1 + 64 * 32;

    for (int k0 = 0; k0 < 1024; k0 += 32) {
        __syncthreads();
        float4 f0 = *(const float4*)(aptr + k0);
        float4 f1 = *(const float4*)(aptr + k0 + 4);
        float4 f2 = *(const float4*)(aptr + k0 + 8);
        float4 f3 = *(const float4*)(aptr + k0 + 12);
        short8 p0, p1;
        p0[0] = f2bf(f0.x); p0[1] = f2bf(f0.y); p0[2] = f2bf(f0.z); p0[3] = f2bf(f0.w);
        p0[4] = f2bf(f1.x); p0[5] = f2bf(f1.y); p0[6] = f2bf(f1.z); p0[7] = f2bf(f1.w);
        p1[0] = f2bf(f2.x); p1[1] = f2bf(f2.y); p1[2] = f2bf(f2.z); p1[3] = f2bf(f2.w);
        p1[4] = f2bf(f3.x); p1[5] = f2bf(f3.y); p1[6] = f2bf(f3.z); p1[7] = f2bf(f3.w);
        *(short8*)adst = p0;
        *(short8*)(adst + 8) = p1;
        *(short8*)bdst1 = *(const short8*)(bptr1 + k0);
        *(short8*)bdst2 = *(const short8*)(bptr2 + k0);
        __syncthreads();

        short8 af[4], bfv[4];
#pragma unroll
        for (int mt = 0; mt < 4; mt++)
            af[mt] = *(const short8*)&As[(wm * 64 + mt * 16 + l15) * 32 + quad * 8];
#pragma unroll
        for (int nt = 0; nt < 4; nt++)
            bfv[nt] = *(const short8*)&Bs[(wn * 64 + nt * 16 + l15) * 32 + quad * 8];
#pragma unroll
        for (int mt = 0; mt < 4; mt++)
#pragma unroll
            for (int nt = 0; nt < 4; nt++)
                acc[mt][nt] = __builtin_amdgcn_mfma_f32_16x16x32_bf16(
                    af[mt], bfv[nt], acc[mt][nt], 0, 0, 0);
    }

    float qn[4], vn[4];
#pragma unroll
    for (int nt = 0; nt < 4; nt++) {
        qn[nt] = q_s[wn * 64 + nt * 16 + l15];
        vn[nt] = v_s[wn * 64 + nt * 16 + l15];
    }
#pragma unroll
    for (int mt = 0; mt < 4; mt++) {
#pragma unroll
        for (int r = 0; r < 4; r++) {
            float sum = 0.f;
#pragma unroll
            for (int nt = 0; nt < 4; nt++)
                sum += vn[nt] * fast_tanh(acc[mt][nt][r] + qn[nt]);
            sum += __shfl_xor(sum, 1, 64);
            sum += __shfl_xor(sum, 2, 64);
            sum += __shfl_xor(sum, 4, 64);
            sum += __shfl_xor(sum, 8, 64);
            if (l15 == 0)
                atomicAdd(&s_acc[wm * 64 + mt * 16 + quad * 4 + r], sum);
        }
    }
    __syncthreads();
    if (t < 128) atomicAdd(&scores[m0 + t], s_acc[t]);
}

__global__ void softmax_kernel(const float* __restrict__ sp, float* __restrict__ attn) {
    int b = blockIdx.x, t = threadIdx.x;
    int w = t >> 6, lane = t & 63;
    __shared__ float rm[4], rs[4];
    float v[8];
#pragma unroll
    for (int i = 0; i < 8; i++) v[i] = sp[(b << 11) + t + (i << 8)];
    float m = v[0];
#pragma unroll
    for (int i = 1; i < 8; i++) m = fmaxf(m, v[i]);
#pragma unroll
    for (int s = 1; s < 64; s <<= 1) m = fmaxf(m, __shfl_xor(m, s, 64));
    if (lane == 0) rm[w] = m;
    __syncthreads();
    m = fmaxf(fmaxf(rm[0], rm[1]), fmaxf(rm[2], rm[3]));
    float s = 0.f;
#pragma unroll
    for (int i = 0; i < 8; i++) { v[i] = __expf(v[i] - m); s += v[i]; }
#pragma unroll
    for (int k = 1; k < 64; k <<= 1) s += __shfl_xor(s, k, 64);
    if (lane == 0) rs[w] = s;
    __syncthreads();
    s = rs[0] + rs[1] + rs[2] + rs[3];
    float inv = 1.f / s;
#pragma unroll
    for (int i = 0; i < 8; i++) attn[(b << 11) + t + (i << 8)] = v[i] * inv;
}

__global__ void context_f32(const float* __restrict__ enc, const float* __restrict__ attn,
                            float* __restrict__ ctx) {
    int dchunk = blockIdx.x, b = blockIdx.y;
    int t = threadIdx.x;
    __shared__ __align__(16) float at_s[2048];
    __shared__ float red[16][128];
    *(float4*)&at_s[t * 4] = *(const float4*)&attn[(b << 11) + t * 4];
    __syncthreads();
    int d4 = (t & 31) << 2;
    int dl = t >> 5;
    int d0 = dchunk << 7;
    const float* base = enc + ((size_t)b << 21) + d0 + d4;
    float ax = 0.f, ay = 0.f, az = 0.f, aw = 0.f;
#pragma unroll 4
    for (int i = 0; i < 128; i++) {
        int l = (i << 4) + dl;
        float wg = at_s[l];
        float4 e = *(const float4*)(base + ((size_t)l << 10));
        ax += wg * e.x; ay += wg * e.y; az += wg * e.z; aw += wg * e.w;
    }
    red[dl][d4 + 0] = ax;
    red[dl][d4 + 1] = ay;
    red[dl][d4 + 2] = az;
    red[dl][d4 + 3] = aw;
    __syncthreads();
    if (t < 128) {
        float s = 0.f;
#pragma unroll
        for (int j = 0; j < 16; j++) s += red[j][t];
        ctx[(b << 10) + d0 + t] = s;
    }
}

extern "C" void kernel_launch(void* const* d_in, const int* in_sizes, int n_in,
                              void* d_out, int out_size, void* d_ws, size_t ws_size,
                              hipStream_t stream) {
    const float* dh  = (const float*)d_in[0];
    const float* enc = (const float*)d_in[1];
    const float* Ww  = (const float*)d_in[2];
    const float* Wb  = (const float*)d_in[3];
    const float* Uw  = (const float*)d_in[4];
    const float* Ub  = (const float*)d_in[5];
    const float* vw  = (const float*)d_in[6];
    // d_in[7] = v_b: dropped (softmax shift-invariance)

    float* out  = (float*)d_out;               // [0,32768) context, [32768,98304) attn
    float* attn = out + BB * DD;
    char*  ws   = (char*)d_ws;
    short* Ubf   = (short*)ws;                           // 2 MB
    float* qbuf  = (float*)(ws + (2 << 20));             // 128 KB
    float* sbuf  = (float*)(ws + (2 << 20) + (1 << 17)); // 2 MB (8 slabs) / 256 KB (B)
    short* encbf = (short*)(ws + (8 << 20));             // 134.2 MB (Path A)

    bool bigws = ws_size >= ((size_t)143 << 20);

    cvt_bf16_kernel<<<512, 256, 0, stream>>>(Uw, Ubf);
    q_kernel<<<512, 256, 0, stream>>>(dh, Ww, Wb, Ub, qbuf);

    if (bigws) {
        cvt_bf16_kernel<<<32768, 256, 0, stream>>>(enc, encbf);
        gemm_scores_bf<<<dim3(8, 512), 256, 0, stream>>>(encbf, Ubf, qbuf, vw, sbuf);
        ctx_softmax_bf<<<dim3(8, BB), 512, 0, stream>>>(sbuf, encbf, attn, out);
    } else {
        hipMemsetAsync(sbuf, 0, (size_t)BB * LL * sizeof(float), stream);
        gemm_scores_f32<<<dim3(8, 512), 256, 0, stream>>>(enc, Ubf, qbuf, vw, sbuf);
        softmax_kernel<<<BB, 256, 0, stream>>>(sbuf, attn);
        context_f32<<<dim3(8, BB), 512, 0, stream>>>(enc, attn, out);
    }
}

// Round 4
// 559.253 us; speedup vs baseline: 1.1748x; 1.0601x over previous
//
#include <hip/hip_runtime.h>
#include <hip/hip_bf16.h>
#include <stdint.h>

#define BB 32
#define LL 2048
#define DD 1024

typedef short short8  __attribute__((ext_vector_type(8)));
typedef float f32x4   __attribute__((ext_vector_type(4)));

__device__ __forceinline__ short f2bf(float f) {
    unsigned u = __float_as_uint(f);
    u += 0x7fffu + ((u >> 16) & 1u);      // round-to-nearest-even
    return (short)(u >> 16);
}

__device__ __forceinline__ float bf2f(unsigned short s) {
    return __uint_as_float(((unsigned)s) << 16);
}

__device__ __forceinline__ float fast_tanh(float x) {
    float e = __expf(2.f * x);
    return 1.f - 2.f * __builtin_amdgcn_rcpf(e + 1.f);
}

__device__ __forceinline__ void async_cp16(const void* g, void* l) {
    __builtin_amdgcn_global_load_lds(
        (__attribute__((address_space(1))) void*)g,
        (__attribute__((address_space(3))) void*)l, 16, 0, 0);
}

// ---------- fused prep: q' + U->bf16 + enc->bf16, one launch ----------
// blocks [0,512): q'[b][d] = Ww[d,:]·h[b,:] + Wb[d] + Ub[d]
// blocks [512,1024): U cvt ; blocks [1024, 33792): enc cvt
__global__ void prep_kernel(const float* __restrict__ dh, const float* __restrict__ Ww,
                            const float* __restrict__ Wb, const float* __restrict__ Ub,
                            const float* __restrict__ Uw, const float* __restrict__ enc,
                            float* __restrict__ qbuf, short* __restrict__ Ubf,
                            short* __restrict__ encbf) {
    const int bid = blockIdx.x, t = threadIdx.x;
    if (bid >= 512) {
        const float* src = (bid < 1024) ? Uw : enc;
        short* dst = (bid < 1024) ? Ubf : encbf;
        int base = (bid < 1024) ? (bid - 512) : (bid - 1024);
        size_t idx = ((size_t)base * 256 + t) * 8;
        float4 a = *(const float4*)(src + idx);
        float4 c = *(const float4*)(src + idx + 4);
        short8 p;
        p[0] = f2bf(a.x); p[1] = f2bf(a.y); p[2] = f2bf(a.z); p[3] = f2bf(a.w);
        p[4] = f2bf(c.x); p[5] = f2bf(c.y); p[6] = f2bf(c.z); p[7] = f2bf(c.w);
        *(short8*)(dst + idx) = p;
        return;
    }
    int b  = bid >> 4;
    int d0 = (bid & 15) << 6;
    int w = t >> 6, lane = t & 63;
    __shared__ __align__(16) float hs[DD];
    *(float4*)&hs[t * 4] = *(const float4*)&dh[b * DD + t * 4];
    __syncthreads();
    float hr[16];
#pragma unroll
    for (int i = 0; i < 16; i++) hr[i] = hs[lane + 64 * i];
    for (int i = 0; i < 16; i++) {
        int d = d0 + w * 16 + i;
        const float* wr = Ww + (size_t)d * DD;
        float s = 0.f;
#pragma unroll
        for (int j = 0; j < 16; j++) s += wr[lane + 64 * j] * hr[j];
#pragma unroll
        for (int m = 1; m < 64; m <<= 1) s += __shfl_xor(s, m, 64);
        if (lane == 0) qbuf[b * DD + d] = s + Wb[d] + Ub[d];
    }
}

// ---------- Path A: bf16 GEMM, XCD-swizzled, BK=64 (2x BK32 sub-buffers) ----------
__global__ __launch_bounds__(256, 3) void gemm_scores_bf(
    const short* __restrict__ encbf, const short* __restrict__ Ubf,
    const float* __restrict__ qbuf, const float* __restrict__ vw,
    float* __restrict__ spart) {
    __shared__ __align__(16) short As[2][128 * 32];
    __shared__ __align__(16) short Bs[2][128 * 32];
    __shared__ float q_s[128], v_s[128], s_acc[2][128];

    const int t = threadIdx.x;
    const int lane = t & 63, w = t >> 6;
    const int l15 = lane & 15, quad = lane >> 4;
    const int wm = w >> 1, wn = w & 1;

    // XCD swizzle: keep the 8 n-blocks of one m-stripe on ONE XCD so the
    // 256 KB A-stripe is fetched into a single L2.
    const int lin  = blockIdx.x + (blockIdx.y << 3);   // 0..4095
    const int xcd  = lin & 7;
    const int slot = lin >> 3;                          // 0..511
    const int nblk = slot & 7;
    const int mstripe = (xcd << 6) + (slot >> 3);       // 0..511
    const int n0 = nblk << 7;
    const int m0 = mstripe << 7;
    const int b  = m0 >> 11;

    if (t < 128) {
        q_s[t] = qbuf[(b << 10) + n0 + t];
        v_s[t] = vw[n0 + t];
    }

    f32x4 acc[4][4];
#pragma unroll
    for (int i = 0; i < 4; i++)
#pragma unroll
        for (int j = 0; j < 4; j++) acc[i][j] = (f32x4){0.f, 0.f, 0.f, 0.f};

    const int srow = lane >> 2, sseg = (lane & 3) << 3;
    const short* gA0 = encbf + (((size_t)(m0 + w * 32 + srow)) << 10) + sseg;
    const short* gB0 = Ubf   + (((size_t)(n0 + w * 32 + srow)) << 10) + sseg;
    const int lofs = w * 32 * 32;

    for (int k0 = 0; k0 < 1024; k0 += 64) {
        __syncthreads();
        async_cp16(gA0 + k0,                 &As[0][lofs]);
        async_cp16(gA0 + k0 + (16 << 10),    &As[0][lofs + 16 * 32]);
        async_cp16(gB0 + k0,                 &Bs[0][lofs]);
        async_cp16(gB0 + k0 + (16 << 10),    &Bs[0][lofs + 16 * 32]);
        async_cp16(gA0 + k0 + 32,            &As[1][lofs]);
        async_cp16(gA0 + k0 + 32 + (16 << 10), &As[1][lofs + 16 * 32]);
        async_cp16(gB0 + k0 + 32,            &Bs[1][lofs]);
        async_cp16(gB0 + k0 + 32 + (16 << 10), &Bs[1][lofs + 16 * 32]);
        __syncthreads();

#pragma unroll
        for (int h = 0; h < 2; h++) {
            short8 af[4], bfv[4];
#pragma unroll
            for (int mt = 0; mt < 4; mt++)
                af[mt] = *(const short8*)&As[h][(wm * 64 + mt * 16 + l15) * 32 + quad * 8];
#pragma unroll
            for (int nt = 0; nt < 4; nt++)
                bfv[nt] = *(const short8*)&Bs[h][(wn * 64 + nt * 16 + l15) * 32 + quad * 8];
#pragma unroll
            for (int mt = 0; mt < 4; mt++)
#pragma unroll
                for (int nt = 0; nt < 4; nt++)
                    acc[mt][nt] = __builtin_amdgcn_mfma_f32_16x16x32_bf16(
                        af[mt], bfv[nt], acc[mt][nt], 0, 0, 0);
        }
    }

    float qn[4], vn[4];
#pragma unroll
    for (int nt = 0; nt < 4; nt++) {
        qn[nt] = q_s[wn * 64 + nt * 16 + l15];
        vn[nt] = v_s[wn * 64 + nt * 16 + l15];
    }
#pragma unroll
    for (int mt = 0; mt < 4; mt++) {
#pragma unroll
        for (int r = 0; r < 4; r++) {
            float sum = 0.f;
#pragma unroll
            for (int nt = 0; nt < 4; nt++)
                sum += vn[nt] * fast_tanh(acc[mt][nt][r] + qn[nt]);
            sum += __shfl_xor(sum, 1, 64);
            sum += __shfl_xor(sum, 2, 64);
            sum += __shfl_xor(sum, 4, 64);
            sum += __shfl_xor(sum, 8, 64);
            if (l15 == 0)
                s_acc[wn][wm * 64 + mt * 16 + quad * 4 + r] = sum;
        }
    }
    __syncthreads();
    if (t < 128)
        spart[((size_t)nblk << 16) + m0 + t] = s_acc[0][t] + s_acc[1][t];
}

// ---------- Path A: fused softmax + context (bf16 enc, L3-resident) ----------
__global__ void ctx_softmax_bf(const float* __restrict__ sp, const short* __restrict__ encbf,
                               float* __restrict__ attn, float* __restrict__ ctx) {
    const int dchunk = blockIdx.x, b = blockIdx.y;
    const int t = threadIdx.x;                 // 0..511
    const int w = t >> 6, lane = t & 63;
    __shared__ float at_s[2048];
    __shared__ float red[16][128];
    __shared__ float rr[8];

    float v[4];
#pragma unroll
    for (int i = 0; i < 4; i++) {
        int l = t + (i << 9);
        float s = 0.f;
#pragma unroll
        for (int p = 0; p < 8; p++) s += sp[(p << 16) + (b << 11) + l];
        v[i] = s;
    }
    float m = fmaxf(fmaxf(v[0], v[1]), fmaxf(v[2], v[3]));
#pragma unroll
    for (int s = 1; s < 64; s <<= 1) m = fmaxf(m, __shfl_xor(m, s, 64));
    if (lane == 0) rr[w] = m;
    __syncthreads();
    m = rr[0];
#pragma unroll
    for (int i = 1; i < 8; i++) m = fmaxf(m, rr[i]);
    float s = 0.f;
#pragma unroll
    for (int i = 0; i < 4; i++) { v[i] = __expf(v[i] - m); s += v[i]; }
#pragma unroll
    for (int k = 1; k < 64; k <<= 1) s += __shfl_xor(s, k, 64);
    __syncthreads();
    if (lane == 0) rr[w] = s;
#pragma unroll
    for (int i = 0; i < 4; i++) at_s[t + (i << 9)] = v[i];
    __syncthreads();
    s = 0.f;
#pragma unroll
    for (int i = 0; i < 8; i++) s += rr[i];
    float inv = 1.f / s;

    if (dchunk == 0) {
#pragma unroll
        for (int i = 0; i < 4; i++) attn[(b << 11) + t + (i << 9)] = v[i] * inv;
    }

    const int d4 = (t & 31) << 2;
    const int dl = t >> 5;
    const int d0 = dchunk << 7;
    const short* base = encbf + ((size_t)b << 21) + d0 + d4;
    float ax = 0.f, ay = 0.f, az = 0.f, aw = 0.f;
#pragma unroll 4
    for (int i = 0; i < 128; i++) {
        int l = (i << 4) + dl;
        float wg = at_s[l];
        ushort4 e = *(const ushort4*)(base + ((size_t)l << 10));
        ax += wg * bf2f(e.x); ay += wg * bf2f(e.y);
        az += wg * bf2f(e.z); aw += wg * bf2f(e.w);
    }
    red[dl][d4 + 0] = ax;
    red[dl][d4 + 1] = ay;
    red[dl][d4 + 2] = az;
    red[dl][d4 + 3] = aw;
    __syncthreads();
    if (t < 128) {
        float acc = 0.f;
#pragma unroll
        for (int j = 0; j < 16; j++) acc += red[j][t];
        ctx[(b << 10) + d0 + t] = acc * inv;
    }
}

// ---------- Path B fallback (small ws) ----------
__global__ void cvt_bf16_kernel(const float* __restrict__ src, short* __restrict__ dst) {
    int idx = (blockIdx.x * 256 + threadIdx.x) * 8;
    float4 a = *(const float4*)(src + idx);
    float4 c = *(const float4*)(src + idx + 4);
    short8 p;
    p[0] = f2bf(a.x); p[1] = f2bf(a.y); p[2] = f2bf(a.z); p[3] = f2bf(a.w);
    p[4] = f2bf(c.x); p[5] = f2bf(c.y); p[6] = f2bf(c.z); p[7] = f2bf(c.w);
    *(short8*)(dst + idx) = p;
}

__global__ void q_kernel(const float* __restrict__ dh, const float* __restrict__ Ww,
                         const float* __restrict__ Wb, const float* __restrict__ Ub,
                         float* __restrict__ qbuf) {
    int b  = blockIdx.x >> 4;
    int d0 = (blockIdx.x & 15) << 6;
    int t = threadIdx.x, w = t >> 6, lane = t & 63;
    __shared__ __align__(16) float hs[DD];
    *(float4*)&hs[t * 4] = *(const float4*)&dh[b * DD + t * 4];
    __syncthreads();
    float hr[16];
#pragma unroll
    for (int i = 0; i < 16; i++) hr[i] = hs[lane + 64 * i];
    for (int i = 0; i < 16; i++) {
        int d = d0 + w * 16 + i;
        const float* wr = Ww + (size_t)d * DD;
        float s = 0.f;
#pragma unroll
        for (int j = 0; j < 16; j++) s += wr[lane + 64 * j] * hr[j];
#pragma unroll
        for (int m = 1; m < 64; m <<= 1) s += __shfl_xor(s, m, 64);
        if (lane == 0) qbuf[b * DD + d] = s + Wb[d] + Ub[d];
    }
}

__global__ __launch_bounds__(256, 3) void gemm_scores_f32(
    const float* __restrict__ enc, const short* __restrict__ Ubf,
    const float* __restrict__ qbuf, const float* __restrict__ vw,
    float* __restrict__ scores) {
    __shared__ __align__(16) short As[128 * 32];
    __shared__ __align__(16) short Bs[128 * 32];
    __shared__ float q_s[128], v_s[128], s_acc[128];

    const int t = threadIdx.x;
    const int lane = t & 63, w = t >> 6;
    const int l15 = lane & 15, quad = lane >> 4;
    const int wm = w >> 1, wn = w & 1;
    const int n0 = blockIdx.x << 7;
    const int m0 = blockIdx.y << 7;
    const int b  = m0 >> 11;

    if (t < 128) {
        q_s[t] = qbuf[(b << 10) + n0 + t];
        v_s[t] = vw[n0 + t];
        s_acc[t] = 0.f;
    }

    f32x4 acc[4][4];
#pragma unroll
    for (int i = 0; i < 4; i++)
#pragma unroll
        for (int j = 0; j < 4; j++) acc[i][j] = (f32x4){0.f, 0.f, 0.f, 0.f};

    const int arow = t >> 1, ahalf = t & 1;
    const float* aptr = enc + (((size_t)(m0 + arow)) << 10) + (ahalf << 4);
    short* adst = As + arow * 32 + ahalf * 16;
    const int brow = t >> 2, bks = (t & 3) * 8;
    const short* bptr1 = Ubf + ((size_t)(n0 + brow)) * 1024 + bks;
    const short* bptr2 = bptr1 + (size_t)64 * 1024;
    short* bdst1 = Bs + brow * 32 + bks;
    short* bdst2 = bdst1 + 64 * 32;

    for (int k0 = 0; k0 < 1024; k0 += 32) {
        __syncthreads();
        float4 f0 = *(const float4*)(aptr + k0);
        float4 f1 = *(const float4*)(aptr + k0 + 4);
        float4 f2 = *(const float4*)(aptr + k0 + 8);
        float4 f3 = *(const float4*)(aptr + k0 + 12);
        short8 p0, p1;
        p0[0] = f2bf(f0.x); p0[1] = f2bf(f0.y); p0[2] = f2bf(f0.z); p0[3] = f2bf(f0.w);
        p0[4] = f2bf(f1.x); p0[5] = f2bf(f1.y); p0[6] = f2bf(f1.z); p0[7] = f2bf(f1.w);
        p1[0] = f2bf(f2.x); p1[1] = f2bf(f2.y); p1[2] = f2bf(f2.z); p1[3] = f2bf(f2.w);
        p1[4] = f2bf(f3.x); p1[5] = f2bf(f3.y); p1[6] = f2bf(f3.z); p1[7] = f2bf(f3.w);
        *(short8*)adst = p0;
        *(short8*)(adst + 8) = p1;
        *(short8*)bdst1 = *(const short8*)(bptr1 + k0);
        *(short8*)bdst2 = *(const short8*)(bptr2 + k0);
        __syncthreads();

        short8 af[4], bfv[4];
#pragma unroll
        for (int mt = 0; mt < 4; mt++)
            af[mt] = *(const short8*)&As[(wm * 64 + mt * 16 + l15) * 32 + quad * 8];
#pragma unroll
        for (int nt = 0; nt < 4; nt++)
            bfv[nt] = *(const short8*)&Bs[(wn * 64 + nt * 16 + l15) * 32 + quad * 8];
#pragma unroll
        for (int mt = 0; mt < 4; mt++)
#pragma unroll
            for (int nt = 0; nt < 4; nt++)
                acc[mt][nt] = __builtin_amdgcn_mfma_f32_16x16x32_bf16(
                    af[mt], bfv[nt], acc[mt][nt], 0, 0, 0);
    }

    float qn[4], vn[4];
#pragma unroll
    for (int nt = 0; nt < 4; nt++) {
        qn[nt] = q_s[wn * 64 + nt * 16 + l15];
        vn[nt] = v_s[wn * 64 + nt * 16 + l15];
    }
#pragma unroll
    for (int mt = 0; mt < 4; mt++) {
#pragma unroll
        for (int r = 0; r < 4; r++) {
            float sum = 0.f;
#pragma unroll
            for (int nt = 0; nt < 4; nt++)
                sum += vn[nt] * fast_tanh(acc[mt][nt][r] + qn[nt]);
            sum += __shfl_xor(sum, 1, 64);
            sum += __shfl_xor(sum, 2, 64);
            sum += __shfl_xor(sum, 4, 64);
            sum += __shfl_xor(sum, 8, 64);
            if (l15 == 0)
                atomicAdd(&s_acc[wm * 64 + mt * 16 + quad * 4 + r], sum);
        }
    }
    __syncthreads();
    if (t < 128) atomicAdd(&scores[m0 + t], s_acc[t]);
}

__global__ void softmax_kernel(const float* __restrict__ sp, float* __restrict__ attn) {
    int b = blockIdx.x, t = threadIdx.x;
    int w = t >> 6, lane = t & 63;
    __shared__ float rm[4], rs[4];
    float v[8];
#pragma unroll
    for (int i = 0; i < 8; i++) v[i] = sp[(b << 11) + t + (i << 8)];
    float m = v[0];
#pragma unroll
    for (int i = 1; i < 8; i++) m = fmaxf(m, v[i]);
#pragma unroll
    for (int s = 1; s < 64; s <<= 1) m = fmaxf(m, __shfl_xor(m, s, 64));
    if (lane == 0) rm[w] = m;
    __syncthreads();
    m = fmaxf(fmaxf(rm[0], rm[1]), fmaxf(rm[2], rm[3]));
    float s = 0.f;
#pragma unroll
    for (int i = 0; i < 8; i++) { v[i] = __expf(v[i] - m); s += v[i]; }
#pragma unroll
    for (int k = 1; k < 64; k <<= 1) s += __shfl_xor(s, k, 64);
    if (lane == 0) rs[w] = s;
    __syncthreads();
    s = rs[0] + rs[1] + rs[2] + rs[3];
    float inv = 1.f / s;
#pragma unroll
    for (int i = 0; i < 8; i++) attn[(b << 11) + t + (i << 8)] = v[i] * inv;
}

__global__ void context_f32(const float* __restrict__ enc, const float* __restrict__ attn,
                            float* __restrict__ ctx) {
    int dchunk = blockIdx.x, b = blockIdx.y;
    int t = threadIdx.x;
    __shared__ __align__(16) float at_s[2048];
    __shared__ float red[16][128];
    *(float4*)&at_s[t * 4] = *(const float4*)&attn[(b << 11) + t * 4];
    __syncthreads();
    int d4 = (t & 31) << 2;
    int dl = t >> 5;
    int d0 = dchunk << 7;
    const float* base = enc + ((size_t)b << 21) + d0 + d4;
    float ax = 0.f, ay = 0.f, az = 0.f, aw = 0.f;
#pragma unroll 4
    for (int i = 0; i < 128; i++) {
        int l = (i << 4) + dl;
        float wg = at_s[l];
        float4 e = *(const float4*)(base + ((size_t)l << 10));
        ax += wg * e.x; ay += wg * e.y; az += wg * e.z; aw += wg * e.w;
    }
    red[dl][d4 + 0] = ax;
    red[dl][d4 + 1] = ay;
    red[dl][d4 + 2] = az;
    red[dl][d4 + 3] = aw;
    __syncthreads();
    if (t < 128) {
        float s = 0.f;
#pragma unroll
        for (int j = 0; j < 16; j++) s += red[j][t];
        ctx[(b << 10) + d0 + t] = s;
    }
}

extern "C" void kernel_launch(void* const* d_in, const int* in_sizes, int n_in,
                              void* d_out, int out_size, void* d_ws, size_t ws_size,
                              hipStream_t stream) {
    const float* dh  = (const float*)d_in[0];
    const float* enc = (const float*)d_in[1];
    const float* Ww  = (const float*)d_in[2];
    const float* Wb  = (const float*)d_in[3];
    const float* Uw  = (const float*)d_in[4];
    const float* Ub  = (const float*)d_in[5];
    const float* vw  = (const float*)d_in[6];
    // d_in[7] = v_b: dropped (softmax shift-invariance)

    float* out  = (float*)d_out;               // [0,32768) context, [32768,98304) attn
    float* attn = out + BB * DD;
    char*  ws   = (char*)d_ws;
    short* Ubf   = (short*)ws;                           // 2 MB
    float* qbuf  = (float*)(ws + (2 << 20));             // 128 KB
    float* sbuf  = (float*)(ws + (2 << 20) + (1 << 17)); // 2 MB (8 slabs) / 256 KB (B)
    short* encbf = (short*)(ws + (8 << 20));             // 134.2 MB (Path A)

    bool bigws = ws_size >= ((size_t)143 << 20);

    if (bigws) {
        prep_kernel<<<33792, 256, 0, stream>>>(dh, Ww, Wb, Ub, Uw, enc, qbuf, Ubf, encbf);
        gemm_scores_bf<<<dim3(8, 512), 256, 0, stream>>>(encbf, Ubf, qbuf, vw, sbuf);
        ctx_softmax_bf<<<dim3(8, BB), 512, 0, stream>>>(sbuf, encbf, attn, out);
    } else {
        hipMemsetAsync(sbuf, 0, (size_t)BB * LL * sizeof(float), stream);
        cvt_bf16_kernel<<<512, 256, 0, stream>>>(Uw, Ubf);
        q_kernel<<<512, 256, 0, stream>>>(dh, Ww, Wb, Ub, qbuf);
        gemm_scores_f32<<<dim3(8, 512), 256, 0, stream>>>(enc, Ubf, qbuf, vw, sbuf);
        softmax_kernel<<<BB, 256, 0, stream>>>(sbuf, attn);
        context_f32<<<dim3(8, BB), 512, 0, stream>>>(enc, attn, out);
    }
}